// Round 4
// baseline (49.977 us; speedup 1.0000x reference)
//
#include <hip/hip_runtime.h>

// out[b, f] = x[b, f] * exp(diagonal[f])
// x: 8192 x 4096 f32, diagonal: 4096 f32, out: 8192 x 4096 f32.
// Memory-bound elementwise. float4 vectorization; exp() hoisted (one column
// quad per thread, reused across 16 rows). Key fix this round: explicit
// 8-deep load batching so 8 global_load_dwordx4 are in flight per thread
// (previous version had VGPR=16 -> single load in flight -> latency-bound
// at 31% of HBM peak).

typedef float f32x4 __attribute__((ext_vector_type(4)));

#define ROWS 8192
#define COLS 4096
#define ROW_F4 (COLS / 4)          // 1024 float4 per row
#define BLOCK 256
#define GRID_X (ROW_F4 / BLOCK)    // 4 column blocks cover a full row
#define GRID_Y 512                 // 2048 blocks: exactly fills 256 CUs
#define RPT 16                     // rows per thread
#define BATCH 8                    // loads in flight

__global__ __launch_bounds__(BLOCK) void Diagonal_73126113181894_kernel(
    const f32x4* __restrict__ x, const float* __restrict__ diagonal,
    f32x4* __restrict__ out) {
  const int col4 = blockIdx.x * BLOCK + threadIdx.x;   // float4 column index
  const f32x4 d = reinterpret_cast<const f32x4*>(diagonal)[col4];
  f32x4 e;
  e.x = expf(d.x);
  e.y = expf(d.y);
  e.z = expf(d.z);
  e.w = expf(d.w);

  const size_t base = (size_t)blockIdx.y * ROW_F4 + col4;
  const size_t stride = (size_t)GRID_Y * ROW_F4;   // 512 rows apart

#pragma unroll
  for (int rr = 0; rr < RPT; rr += BATCH) {
    f32x4 v[BATCH];
    // Phase 1: issue all BATCH loads (independent -> stay in flight together)
#pragma unroll
    for (int j = 0; j < BATCH; ++j)
      v[j] = x[base + (size_t)(rr + j) * stride];
    // Phase 2: multiply + store
#pragma unroll
    for (int j = 0; j < BATCH; ++j)
      out[base + (size_t)(rr + j) * stride] = v[j] * e;
  }
}

extern "C" void kernel_launch(void* const* d_in, const int* in_sizes, int n_in,
                              void* d_out, int out_size, void* d_ws, size_t ws_size,
                              hipStream_t stream) {
  const f32x4* x = (const f32x4*)d_in[0];
  const float* diagonal = (const float*)d_in[1];
  f32x4* out = (f32x4*)d_out;

  dim3 grid(GRID_X, GRID_Y, 1);
  dim3 block(BLOCK, 1, 1);
  Diagonal_73126113181894_kernel<<<grid, block, 0, stream>>>(x, diagonal, out);
}

// Round 5
// 45.445 us; speedup vs baseline: 1.0997x; 1.0997x over previous
//
#include <hip/hip_runtime.h>

// out[b, f] = x[b, f] * exp(diagonal[f])
// x: 8192 x 4096 f32, diagonal: 4096 f32, out: 8192 x 4096 f32.
// Memory-bound elementwise op. float4 vectorization, exp() hoisted out of
// the row loop (each thread owns a fixed column quad across 16 rows).
//
// Round history: R1 (this kernel) = 45.7 us = 5.87 TB/s fabric traffic
// (268 MB), 93% of the 6.29 TB/s measured D2D-copy ceiling.
// R3 nt-store = 48.7 us (L3 retention not steered by nt; reverted).
// R4 8-deep ILP batch = 50.0 us (forced ILP lengthens per-wave critical
// path; wave-level TLP at VGPR=16 already covers latency; reverted).

#define ROWS 8192
#define COLS 4096
#define ROW_F4 (COLS / 4)          // 1024 float4 per row
#define BLOCK 256
#define GRID_X (ROW_F4 / BLOCK)    // 4 column blocks cover a full row
#define GRID_Y 512                 // 2048 blocks total; 16 rows per thread

__global__ __launch_bounds__(BLOCK) void Diagonal_73126113181894_kernel(
    const float4* __restrict__ x, const float* __restrict__ diagonal,
    float4* __restrict__ out) {
  const int col4 = blockIdx.x * BLOCK + threadIdx.x;   // float4 column index
  // Load this thread's 4 diagonal values once, exp once, reuse for all rows.
  const float4 d = reinterpret_cast<const float4*>(diagonal)[col4];
  float4 e;
  e.x = expf(d.x);
  e.y = expf(d.y);
  e.z = expf(d.z);
  e.w = expf(d.w);

#pragma unroll 4
  for (int r = blockIdx.y; r < ROWS; r += GRID_Y) {
    const size_t idx = (size_t)r * ROW_F4 + col4;
    float4 v = x[idx];
    v.x *= e.x;
    v.y *= e.y;
    v.z *= e.z;
    v.w *= e.w;
    out[idx] = v;
  }
}

extern "C" void kernel_launch(void* const* d_in, const int* in_sizes, int n_in,
                              void* d_out, int out_size, void* d_ws, size_t ws_size,
                              hipStream_t stream) {
  const float4* x = (const float4*)d_in[0];
  const float* diagonal = (const float*)d_in[1];
  float4* out = (float4*)d_out;

  dim3 grid(GRID_X, GRID_Y, 1);
  dim3 block(BLOCK, 1, 1);
  Diagonal_73126113181894_kernel<<<grid, block, 0, stream>>>(x, diagonal, out);
}